// Round 1
// baseline (552.557 us; speedup 1.0000x reference)
//
#include <hip/hip_runtime.h>
#include <hip/hip_bf16.h>
#include <math.h>

typedef __hip_bfloat16 bf16;
typedef __attribute__((ext_vector_type(4))) float f32x4;
typedef __attribute__((ext_vector_type(8))) short short8;
typedef __attribute__((ext_vector_type(4))) unsigned int u32x4;

#define HIDN 768
#define NTOK 2048   // B*S
#define NH 12
#define HD 64
#define ISZ 3072
#define SEQ 512

__device__ __forceinline__ bf16 f2bf(float x){ return __float2bfloat16(x); }
__device__ __forceinline__ float gelu_f(float x){ return 0.5f*x*(1.0f + erff(x*0.70710678118654752f)); }

// ---------------------------------------------------------------------------
// Generic bf16 GEMM: C = A[M,K] @ B[N,K]^T  (both operands K-major)
// 128x128 tile, BK=32, 256 threads = 4 waves, each wave 64x64 (4x4 frags of
// 16x16x32 MFMA). Reg-staged LDS (single buffer, 2 barriers per K-step).
// Batched over blockIdx.z: absolute z = zb0+bz decomposed as zq=z/zdiv,
// zr=z%zdiv; A/B/bias use (zq,zr,bz) strides, C uses (zq,zr,bz) strides.
// EPI: 0 = bias, bf16 out          (QKV)
//      1 = scale[zq]*(v+bias), bf16 (per-head Wo, scale=w_kp)
//      2 = gelu(v+bias), bf16       (FFN1)
//      3 = v*scale[base+row>>11], f32 (FFN2, scale=w_a)
//      4 = v*0.125 + bias[col], f32 (attention scores + mask)
//      5 = bf16 out, col<Nvalid guard (PV)
// ---------------------------------------------------------------------------
template<int EPI>
__global__ __launch_bounds__(256)
void gemm_bt(const bf16* __restrict__ Abase, const bf16* __restrict__ Bbase,
             void* __restrict__ Cbase, const float* __restrict__ biasBase,
             const float* __restrict__ scales,
             int K, int lda, int ldb, int ldc, int Nvalid,
             int zb0, int zdiv, int scale_base,
             long sAq, long sAr, long sAz,
             long sBq, long sBr, long sBz,
             long sCq, long sCr, long sCz,
             long sBiasq)
{
    int bz = blockIdx.z;
    int za = zb0 + bz;
    int zq = za / zdiv, zr = za - zq*zdiv;
    const bf16* A = Abase + (long)zq*sAq + (long)zr*sAr + (long)bz*sAz;
    const bf16* B = Bbase + (long)zq*sBq + (long)zr*sBr + (long)bz*sBz;
    const float* bias = biasBase ? (biasBase + (long)zq*sBiasq) : nullptr;
    long coff = (long)zq*sCq + (long)zr*sCr + (long)bz*sCz;

    __shared__ bf16 As[128*32];
    __shared__ bf16 Bs[128*32];

    int bn = blockIdx.x, bm = blockIdx.y;
    int t = threadIdx.x;
    int wave = t >> 6, lane = t & 63;
    int wm = (wave >> 1) << 6;   // 0 or 64
    int wn = (wave & 1) << 6;
    int lr = lane & 15, lg = lane >> 4;

    f32x4 acc[4][4] = {};

    int arow = t >> 2;              // 0..63
    int acol = (t & 3) << 3;        // 0,8,16,24
    const bf16* Aptr = A + (long)(bm*128 + arow)*lda + acol;
    const bf16* Bptr = B + (long)(bn*128 + arow)*ldb + acol;

    for (int k0 = 0; k0 < K; k0 += 32) {
        u32x4 ra0 = *(const u32x4*)(Aptr);
        u32x4 ra1 = *(const u32x4*)(Aptr + (long)64*lda);
        u32x4 rb0 = *(const u32x4*)(Bptr);
        u32x4 rb1 = *(const u32x4*)(Bptr + (long)64*ldb);
        Aptr += 32; Bptr += 32;
        __syncthreads();
        *(u32x4*)&As[arow*32 + acol]      = ra0;
        *(u32x4*)&As[(arow+64)*32 + acol] = ra1;
        *(u32x4*)&Bs[arow*32 + acol]      = rb0;
        *(u32x4*)&Bs[(arow+64)*32 + acol] = rb1;
        __syncthreads();
        short8 af[4], bfr[4];
        #pragma unroll
        for (int m=0;m<4;m++) af[m]  = *(short8*)&As[(wm + m*16 + lr)*32 + lg*8];
        #pragma unroll
        for (int n=0;n<4;n++) bfr[n] = *(short8*)&Bs[(wn + n*16 + lr)*32 + lg*8];
        #pragma unroll
        for (int m=0;m<4;m++)
            #pragma unroll
            for (int n=0;n<4;n++)
                acc[m][n] = __builtin_amdgcn_mfma_f32_16x16x32_bf16(af[m], bfr[n], acc[m][n], 0,0,0);
    }

    // epilogue: C/D layout col=lane&15, row=(lane>>4)*4 + i  [m89/m91 verified]
    #pragma unroll
    for (int m=0;m<4;m++){
        #pragma unroll
        for (int n=0;n<4;n++){
            int col = bn*128 + wn + n*16 + lr;
            float bcol = 0.f;
            if constexpr (EPI==0||EPI==1||EPI==2||EPI==4) bcol = bias[col];
            #pragma unroll
            for (int i=0;i<4;i++){
                long row = (long)bm*128 + wm + m*16 + lg*4 + i;
                float v = acc[m][n][i];
                if constexpr (EPI==0){
                    ((bf16*)Cbase + coff)[row*ldc+col] = f2bf(v + bcol);
                } else if constexpr (EPI==1){
                    ((bf16*)Cbase + coff)[row*ldc+col] = f2bf(scales[zq]*(v + bcol));
                } else if constexpr (EPI==2){
                    ((bf16*)Cbase + coff)[row*ldc+col] = f2bf(gelu_f(v + bcol));
                } else if constexpr (EPI==3){
                    ((float*)Cbase + coff)[row*ldc+col] = v * scales[scale_base + (int)(row>>11)];
                } else if constexpr (EPI==4){
                    ((float*)Cbase + coff)[row*ldc+col] = v*0.125f + bcol;
                } else {
                    if (col < Nvalid) ((bf16*)Cbase + coff)[row*ldc+col] = f2bf(v);
                }
            }
        }
    }
}

// ---------------------------------------------------------------------------
// transpose + f32->bf16 convert: src[R][C] -> dst[C][R], batched over z
// ---------------------------------------------------------------------------
__global__ __launch_bounds__(256)
void transpose_cvt(const float* __restrict__ src, bf16* __restrict__ dst,
                   int R, int C, long sSrcZ, long sDstZ)
{
    __shared__ float tile[32][33];
    src += (long)blockIdx.z * sSrcZ;
    dst += (long)blockIdx.z * sDstZ;
    int c0 = blockIdx.x*32, r0 = blockIdx.y*32;
    int tx = threadIdx.x & 31, ty = threadIdx.x >> 5;
    #pragma unroll
    for (int i=0;i<32;i+=8) tile[ty+i][tx] = src[(long)(r0+ty+i)*C + c0+tx];
    __syncthreads();
    #pragma unroll
    for (int i=0;i<32;i+=8) dst[(long)(c0+ty+i)*R + r0+tx] = f2bf(tile[tx][ty+i]);
}

// bf16 V transpose: per z=(b,h): qkv V-slice [512 s][64 d] -> Vt[z][64 d][512 s]
__global__ __launch_bounds__(256)
void transpose_v(const bf16* __restrict__ qkv, bf16* __restrict__ Vt, int zb0)
{
    __shared__ bf16 tile[32][33];
    int za = zb0 + blockIdx.z; int b = za/NH, h = za - b*NH;
    const bf16* src = qkv + (long)b*SEQ*3*HIDN + 2*HIDN + h*HD;
    bf16* dst = Vt + (long)blockIdx.z*128*SEQ;
    int d0 = blockIdx.x*32, s0 = blockIdx.y*32;
    int tx = threadIdx.x & 31, ty = threadIdx.x >> 5;
    #pragma unroll
    for (int i=0;i<32;i+=8) tile[ty+i][tx] = src[(long)(s0+ty+i)*(3*HIDN) + d0+tx];
    __syncthreads();
    #pragma unroll
    for (int i=0;i<32;i+=8) dst[(long)(d0+ty+i)*SEQ + s0+tx] = tile[tx][ty+i];
}

__global__ void cvt_bf16(const float* __restrict__ in, bf16* __restrict__ out, int n){
    int i = blockIdx.x*blockDim.x + threadIdx.x;
    if (i < n) out[i] = f2bf(in[i]);
}

__global__ void concat_bias(const float* __restrict__ bq, const float* __restrict__ bk,
                            const float* __restrict__ bv, float* __restrict__ bqkv){
    int i = blockIdx.x*blockDim.x + threadIdx.x;
    if (i < 3*HIDN) bqkv[i] = (i < HIDN) ? bq[i] : (i < 2*HIDN ? bk[i-HIDN] : bv[i-2*HIDN]);
}

// one block per row of 512 scores
__global__ __launch_bounds__(256)
void softmax_rows(const float* __restrict__ scores, bf16* __restrict__ probs)
{
    __shared__ float red[8];
    long row = blockIdx.x;
    const float* s = scores + row*SEQ;
    bf16* p = probs + row*SEQ;
    int t = threadIdx.x;
    int wave = t>>6, lane = t&63;
    float a = s[t], b2 = s[t+256];
    float m = fmaxf(a,b2);
    #pragma unroll
    for (int o=32;o>0;o>>=1) m = fmaxf(m, __shfl_xor(m,o,64));
    if (lane==0) red[wave]=m;
    __syncthreads();
    m = fmaxf(fmaxf(red[0],red[1]),fmaxf(red[2],red[3]));
    float e0 = __expf(a-m), e1 = __expf(b2-m);
    float sum = e0+e1;
    #pragma unroll
    for (int o=32;o>0;o>>=1) sum += __shfl_xor(sum,o,64);
    __syncthreads();
    if (lane==0) red[4+wave]=sum;
    __syncthreads();
    sum = red[4]+red[5]+red[6]+red[7];
    float inv = 1.0f/sum;
    p[t]     = f2bf(e0*inv);
    p[t+256] = f2bf(e1*inv);
}

__global__ void accum_heads(float* __restrict__ out_acc, const float* __restrict__ outh,
                            int HC, int init){
    int i = blockIdx.x*blockDim.x + threadIdx.x;
    if (i >= NTOK*HIDN) return;
    float s = init ? 0.f : out_acc[i];
    for (int h=0;h<HC;h++) s += outh[(long)h*NTOK*HIDN + i];
    out_acc[i] = s;
}

// out = LN(hidden + out_acc + (sum w_a)*bout)
__global__ __launch_bounds__(256)
void add_ln(const float* __restrict__ hidden, const float* __restrict__ out_acc,
            const float* __restrict__ bout, const float* __restrict__ w_a,
            const float* __restrict__ gamma, const float* __restrict__ beta,
            float* __restrict__ out)
{
    __shared__ float red[8];
    int row = blockIdx.x;
    int t = threadIdx.x;
    int wave = t>>6, lane = t&63;
    float swa = 0.f;
    #pragma unroll
    for (int h=0;h<NH;h++) swa += w_a[h];
    float x[3];
    float sum = 0.f;
    #pragma unroll
    for (int j=0;j<3;j++){
        int c = j*256 + t;
        x[j] = hidden[(long)row*HIDN + c] + out_acc[(long)row*HIDN + c] + swa*bout[c];
        sum += x[j];
    }
    #pragma unroll
    for (int o=32;o>0;o>>=1) sum += __shfl_xor(sum,o,64);
    if (lane==0) red[wave]=sum;
    __syncthreads();
    sum = red[0]+red[1]+red[2]+red[3];
    float u = sum * (1.0f/768.0f);
    float vs = 0.f;
    #pragma unroll
    for (int j=0;j<3;j++){ float d = x[j]-u; vs += d*d; }
    #pragma unroll
    for (int o=32;o>0;o>>=1) vs += __shfl_xor(vs,o,64);
    __syncthreads();
    if (lane==0) red[4+wave]=vs;
    __syncthreads();
    vs = red[4]+red[5]+red[6]+red[7];
    float rstd = rsqrtf(vs*(1.0f/768.0f) + 1e-12f);
    #pragma unroll
    for (int j=0;j<3;j++){
        int c = j*256 + t;
        out[(long)row*HIDN + c] = gamma[c]*(x[j]-u)*rstd + beta[c];
    }
}

extern "C" void kernel_launch(void* const* d_in, const int* in_sizes, int n_in,
                              void* d_out, int out_size, void* d_ws, size_t ws_size,
                              hipStream_t stream)
{
    const float* hidden = (const float*)d_in[0];
    const float* mask   = (const float*)d_in[1];
    const float* Wq = (const float*)d_in[2];
    const float* bq = (const float*)d_in[3];
    const float* Wk = (const float*)d_in[4];
    const float* bk = (const float*)d_in[5];
    const float* Wv = (const float*)d_in[6];
    const float* bv = (const float*)d_in[7];
    const float* Wo = (const float*)d_in[8];
    const float* bo = (const float*)d_in[9];
    const float* w_kp = (const float*)d_in[10];
    const float* w_a  = (const float*)d_in[11];
    const float* Wi = (const float*)d_in[12];
    const float* bi = (const float*)d_in[13];
    const float* Wout = (const float*)d_in[14];
    const float* boutp = (const float*)d_in[15];
    const float* gamma = (const float*)d_in[16];
    const float* beta  = (const float*)d_in[17];
    float* out = (float*)d_out;

    char* w = (char*)d_ws;
    auto alloc = [&](size_t bytes)->char* {
        char* p = w; w += (bytes + 255) & ~(size_t)255; return p;
    };
    bf16*  hbf    = (bf16*) alloc((size_t)NTOK*HIDN*2);
    bf16*  WqkvT  = (bf16*) alloc((size_t)3*HIDN*HIDN*2);
    float* bqkv   = (float*)alloc((size_t)3*HIDN*4);
    bf16*  WoT    = (bf16*) alloc((size_t)NH*HIDN*HD*2);
    bf16*  WiT    = (bf16*) alloc((size_t)ISZ*HIDN*2);
    bf16*  WoutT  = (bf16*) alloc((size_t)HIDN*ISZ*2);
    bf16*  qkv    = (bf16*) alloc((size_t)NTOK*3*HIDN*2);
    bf16*  ctx    = (bf16*) alloc((size_t)NH*NTOK*HD*2);
    float* out_acc= (float*)alloc((size_t)NTOK*HIDN*4);
    size_t fixed = (size_t)(w - (char*)d_ws);
    size_t avail = ws_size > fixed ? ws_size - fixed : 0;

    // attention group size ZB (z = (b,h) pairs processed together)
    const size_t perZ = (size_t)SEQ*SEQ*4 + (size_t)SEQ*SEQ*2 + (size_t)128*SEQ*2;
    int ZB = 48;
    while (ZB > 6 && perZ*(size_t)ZB > avail) ZB >>= 1;
    // FFN head chunk HC
    const size_t perH = (size_t)NTOK*HIDN*2 + (size_t)NTOK*ISZ*2 + (size_t)NTOK*HIDN*4;
    static const int hcs[6] = {12,6,4,3,2,1};
    int HC = 1;
    for (int i=0;i<6;i++){ if (perH*(size_t)hcs[i] <= avail){ HC = hcs[i]; break; } }

    char* big = w;   // shared region: attention views, then FFN chunk views
    float* scores = (float*)big;
    bf16*  probs  = (bf16*)(big + (size_t)ZB*SEQ*SEQ*4);
    bf16*  Vt     = (bf16*)(big + (size_t)ZB*SEQ*SEQ*4 + (size_t)ZB*SEQ*SEQ*2);
    bf16*  xbuf   = (bf16*)big;
    bf16*  inter  = (bf16*)(big + (size_t)HC*NTOK*HIDN*2);
    float* outh   = (float*)(big + (size_t)HC*NTOK*HIDN*2 + (size_t)HC*NTOK*ISZ*2);

    // ---- prep: convert / transpose weights ----
    cvt_bf16<<<(NTOK*HIDN+255)/256, 256, 0, stream>>>(hidden, hbf, NTOK*HIDN);
    concat_bias<<<(3*HIDN+255)/256, 256, 0, stream>>>(bq, bk, bv, bqkv);
    transpose_cvt<<<dim3(HIDN/32, HIDN/32, 1), 256, 0, stream>>>(Wq, WqkvT,              HIDN, HIDN, 0, 0);
    transpose_cvt<<<dim3(HIDN/32, HIDN/32, 1), 256, 0, stream>>>(Wk, WqkvT + HIDN*HIDN,  HIDN, HIDN, 0, 0);
    transpose_cvt<<<dim3(HIDN/32, HIDN/32, 1), 256, 0, stream>>>(Wv, WqkvT + 2*HIDN*HIDN,HIDN, HIDN, 0, 0);
    transpose_cvt<<<dim3(ISZ/32,  HIDN/32, 1), 256, 0, stream>>>(Wi,   WiT,   HIDN, ISZ, 0, 0);
    transpose_cvt<<<dim3(HIDN/32, ISZ/32,  1), 256, 0, stream>>>(Wout, WoutT, ISZ, HIDN, 0, 0);
    transpose_cvt<<<dim3(HIDN/32, HD/32,  NH), 256, 0, stream>>>(Wo,   WoT,   HD, HIDN,
                                                                 (long)HD*HIDN, (long)HIDN*HD);

    // ---- QKV projection: [2048,768] @ [2304,768]^T ----
    gemm_bt<0><<<dim3(3*HIDN/128, NTOK/128, 1), 256, 0, stream>>>(
        hbf, WqkvT, qkv, bqkv, nullptr,
        HIDN, HIDN, HIDN, 3*HIDN, 3*HIDN,
        0, 1, 0,
        0,0,0, 0,0,0, 0,0,0, 0);

    // ---- attention ----
    hipMemsetAsync(Vt, 0, (size_t)ZB*128*SEQ*2, stream);  // zero-pad Vt rows 64..127
    for (int g = 0; g < 48; g += ZB) {
        transpose_v<<<dim3(2,16,ZB), 256, 0, stream>>>(qkv, Vt, g);
        // scores[bz][q][k] = (Q_bh @ K_bh^T)*0.125 + mask[b][k]
        gemm_bt<4><<<dim3(SEQ/128, SEQ/128, ZB), 256, 0, stream>>>(
            qkv, qkv + HIDN, scores, mask, nullptr,
            HD, 3*HIDN, 3*HIDN, SEQ, SEQ,
            g, NH, 0,
            (long)SEQ*3*HIDN, HD, 0,
            (long)SEQ*3*HIDN, HD, 0,
            0, 0, (long)SEQ*SEQ,
            SEQ);
        softmax_rows<<<ZB*SEQ, 256, 0, stream>>>(scores, probs);
        // ctx[h][b*512+s][d] = probs @ V  (N=64 valid of 128)
        gemm_bt<5><<<dim3(1, SEQ/128, ZB), 256, 0, stream>>>(
            probs, Vt, ctx, nullptr, nullptr,
            SEQ, SEQ, SEQ, HD, HD,
            g, NH, 0,
            0, 0, (long)SEQ*SEQ,
            0, 0, (long)128*SEQ,
            (long)SEQ*HD, (long)NTOK*HD, 0,
            0);
    }

    // ---- per-head Wo -> FFN, in chunks of HC heads ----
    for (int c = 0; c < NH; c += HC) {
        // x[h_local] = w_kp[h]*(ctx_h @ Wo_h^T + bo_h)   [2048,64]@[768,64]^T
        gemm_bt<1><<<dim3(HIDN/128, NTOK/128, HC), 256, 0, stream>>>(
            ctx, WoT, xbuf, bo, w_kp,
            HD, HD, HD, HIDN, HIDN,
            c, 1, 0,
            (long)NTOK*HD, 0, 0,
            (long)HIDN*HD, 0, 0,
            0, 0, (long)NTOK*HIDN,
            HIDN);
        // inter = gelu(x @ Wi^T + bi)   [HC*2048,768]@[3072,768]^T
        gemm_bt<2><<<dim3(ISZ/128, HC*NTOK/128, 1), 256, 0, stream>>>(
            xbuf, WiT, inter, bi, nullptr,
            HIDN, HIDN, HIDN, ISZ, ISZ,
            0, 1, 0,
            0,0,0, 0,0,0, 0,0,0, 0);
        // outh = w_a[h]*(inter @ Wout^T)   [HC*2048,3072]@[768,3072]^T
        gemm_bt<3><<<dim3(HIDN/128, HC*NTOK/128, 1), 256, 0, stream>>>(
            inter, WoutT, outh, nullptr, w_a,
            ISZ, ISZ, ISZ, HIDN, HIDN,
            0, 1, c,
            0,0,0, 0,0,0, 0,0,0, 0);
        accum_heads<<<(NTOK*HIDN+255)/256, 256, 0, stream>>>(out_acc, outh, HC, c==0);
    }

    // ---- residual + sum(w_a)*bout + LayerNorm ----
    add_ln<<<NTOK, 256, 0, stream>>>(hidden, out_acc, boutp, w_a, gamma, beta, out);
}

// Round 2
// 496.769 us; speedup vs baseline: 1.1123x; 1.1123x over previous
//
#include <hip/hip_runtime.h>
#include <hip/hip_bf16.h>
#include <math.h>

typedef __hip_bfloat16 bf16;
typedef __attribute__((ext_vector_type(4))) float f32x4;
typedef __attribute__((ext_vector_type(8))) short short8;

#define HIDN 768
#define NTOK 2048   // B*S
#define NH 12
#define HD 64
#define ISZ 3072
#define SEQ 512

__device__ __forceinline__ bf16 f2bf(float x){ return __float2bfloat16(x); }
__device__ __forceinline__ float gelu_f(float x){ return 0.5f*x*(1.0f + erff(x*0.70710678118654752f)); }

// async global->LDS, 16B per lane (m97 pattern: LDS dest = wave base + lane*16)
__device__ __forceinline__ void gload16(const bf16* g, bf16* l){
    __builtin_amdgcn_global_load_lds(
        (const __attribute__((address_space(1))) unsigned int*)g,
        (__attribute__((address_space(3))) unsigned int*)l,
        16, 0, 0);
}

// ---------------------------------------------------------------------------
// Generic bf16 GEMM: C = A[M,K] @ B[N,K]^T  (both operands K-major)
// 128x128 tile, BK=32, 256 threads = 4 waves, each wave 64x64 (4x4 frags of
// 16x16x32 MFMA). global_load_lds width-16 staging (m97 structure).
// XCD-bijective blockIdx swizzle in the x-y plane.
// EPI: 0 = bias, bf16 out              (QKV)
//      1 = scale[zq]*(v+bias), bf16    (per-head Wo, scale=w_kp)
//      2 = gelu(v+bias), bf16          (FFN1)
//      3 = atomicAdd(out_acc, v*scale[base+row>>11]), f32 (FFN2, scale=w_a)
//      4 = v*0.125 + bias[col], f32    (attention scores + mask)
//      5 = bf16 out, col<Nvalid guard  (PV)
// ---------------------------------------------------------------------------
template<int EPI>
__global__ __launch_bounds__(256)
void gemm_bt(const bf16* __restrict__ Abase, const bf16* __restrict__ Bbase,
             void* __restrict__ Cbase, const float* __restrict__ biasBase,
             const float* __restrict__ scales,
             int K, int lda, int ldb, int ldc, int Nvalid,
             int zb0, int zdiv, int scale_base,
             long sAq, long sAr, long sAz,
             long sBq, long sBr, long sBz,
             long sCq, long sCr, long sCz,
             long sBiasq)
{
    int bz = blockIdx.z;
    int za = zb0 + bz;
    int zq = za / zdiv, zr = za - zq*zdiv;
    const bf16* A = Abase + (long)zq*sAq + (long)zr*sAr + (long)bz*sAz;
    const bf16* B = Bbase + (long)zq*sBq + (long)zr*sBr + (long)bz*sBz;
    const float* bias = biasBase ? (biasBase + (long)zq*sBiasq) : nullptr;
    long coff = (long)zq*sCq + (long)zr*sCr + (long)bz*sCz;

    __shared__ bf16 As[128*32];
    __shared__ bf16 Bs[128*32];

    // XCD-aware bijective swizzle (m204 variant) within the x-y plane
    int nwg  = gridDim.x * gridDim.y;
    int orig = blockIdx.y * gridDim.x + blockIdx.x;
    int q8 = nwg >> 3, r8 = nwg & 7;
    int xcd = orig & 7, idx = orig >> 3;
    int wg = (xcd < r8 ? xcd*(q8+1) : r8*(q8+1) + (xcd-r8)*q8) + idx;
    int bn = wg % gridDim.x, bm = wg / gridDim.x;

    int t = threadIdx.x;
    int wave = t >> 6, lane = t & 63;
    int wm = (wave >> 1) << 6;   // 0 or 64
    int wn = (wave & 1) << 6;
    int lr = lane & 15, lg = lane >> 4;

    f32x4 acc[4][4] = {};

    int arow = t >> 2;              // 0..63
    int acol = (t & 3) << 3;        // 0,8,16,24
    const bf16* Ag0 = A + (long)(bm*128 + arow)*lda + acol;
    const bf16* Ag1 = Ag0 + (long)64*lda;
    const bf16* Bg0 = B + (long)(bn*128 + arow)*ldb + acol;
    const bf16* Bg1 = Bg0 + (long)64*ldb;
    bf16* Al = As + t*8;   // thread t's 16B slot == row-major [t/4][(t%4)*8]
    bf16* Bl = Bs + t*8;

    for (int k0 = 0; k0 < K; k0 += 32) {
        __syncthreads();                 // previous iter's ds_reads done
        gload16(Ag0, Al);
        gload16(Ag1, Al + 64*32);
        gload16(Bg0, Bl);
        gload16(Bg1, Bl + 64*32);
        Ag0 += 32; Ag1 += 32; Bg0 += 32; Bg1 += 32;
        __syncthreads();                 // vmcnt(0) drain -> LDS ready
        short8 af[4], bfr[4];
        #pragma unroll
        for (int m=0;m<4;m++) af[m]  = *(short8*)&As[(wm + m*16 + lr)*32 + lg*8];
        #pragma unroll
        for (int n=0;n<4;n++) bfr[n] = *(short8*)&Bs[(wn + n*16 + lr)*32 + lg*8];
        #pragma unroll
        for (int m=0;m<4;m++)
            #pragma unroll
            for (int n=0;n<4;n++)
                acc[m][n] = __builtin_amdgcn_mfma_f32_16x16x32_bf16(af[m], bfr[n], acc[m][n], 0,0,0);
    }

    // epilogue: C/D layout col=lane&15, row=(lane>>4)*4 + i  [m89/m91 verified]
    #pragma unroll
    for (int m=0;m<4;m++){
        #pragma unroll
        for (int n=0;n<4;n++){
            int col = bn*128 + wn + n*16 + lr;
            float bcol = 0.f;
            if constexpr (EPI==0||EPI==1||EPI==2||EPI==4) bcol = bias[col];
            #pragma unroll
            for (int i=0;i<4;i++){
                long row = (long)bm*128 + wm + m*16 + lg*4 + i;
                float v = acc[m][n][i];
                if constexpr (EPI==0){
                    ((bf16*)Cbase + coff)[row*ldc+col] = f2bf(v + bcol);
                } else if constexpr (EPI==1){
                    ((bf16*)Cbase + coff)[row*ldc+col] = f2bf(scales[zq]*(v + bcol));
                } else if constexpr (EPI==2){
                    ((bf16*)Cbase + coff)[row*ldc+col] = f2bf(gelu_f(v + bcol));
                } else if constexpr (EPI==3){
                    float* dst = (float*)Cbase + coff;
                    unsafeAtomicAdd(&dst[(row & (NTOK-1))*ldc + col],
                                    v * scales[scale_base + (int)(row>>11)]);
                } else if constexpr (EPI==4){
                    ((float*)Cbase + coff)[row*ldc+col] = v*0.125f + bcol;
                } else {
                    if (col < Nvalid) ((bf16*)Cbase + coff)[row*ldc+col] = f2bf(v);
                }
            }
        }
    }
}

// ---------------------------------------------------------------------------
// transpose + f32->bf16 convert: src[R][C] -> dst[C][R], batched over z
// ---------------------------------------------------------------------------
__global__ __launch_bounds__(256)
void transpose_cvt(const float* __restrict__ src, bf16* __restrict__ dst,
                   int R, int C, long sSrcZ, long sDstZ)
{
    __shared__ float tile[32][33];
    src += (long)blockIdx.z * sSrcZ;
    dst += (long)blockIdx.z * sDstZ;
    int c0 = blockIdx.x*32, r0 = blockIdx.y*32;
    int tx = threadIdx.x & 31, ty = threadIdx.x >> 5;
    #pragma unroll
    for (int i=0;i<32;i+=8) tile[ty+i][tx] = src[(long)(r0+ty+i)*C + c0+tx];
    __syncthreads();
    #pragma unroll
    for (int i=0;i<32;i+=8) dst[(long)(c0+ty+i)*R + r0+tx] = f2bf(tile[tx][ty+i]);
}

// bf16 V transpose: per z=(b,h): qkv V-slice [512 s][64 d] -> Vt[z][64 d][512 s]
__global__ __launch_bounds__(256)
void transpose_v(const bf16* __restrict__ qkv, bf16* __restrict__ Vt, int zb0)
{
    __shared__ bf16 tile[32][33];
    int za = zb0 + blockIdx.z; int b = za/NH, h = za - b*NH;
    const bf16* src = qkv + (long)b*SEQ*3*HIDN + 2*HIDN + h*HD;
    bf16* dst = Vt + (long)blockIdx.z*128*SEQ;
    int d0 = blockIdx.x*32, s0 = blockIdx.y*32;
    int tx = threadIdx.x & 31, ty = threadIdx.x >> 5;
    #pragma unroll
    for (int i=0;i<32;i+=8) tile[ty+i][tx] = src[(long)(s0+ty+i)*(3*HIDN) + d0+tx];
    __syncthreads();
    #pragma unroll
    for (int i=0;i<32;i+=8) dst[(long)(d0+ty+i)*SEQ + s0+tx] = tile[tx][ty+i];
}

__global__ void cvt_bf16(const float* __restrict__ in, bf16* __restrict__ out, int n){
    int i = blockIdx.x*blockDim.x + threadIdx.x;
    if (i < n) out[i] = f2bf(in[i]);
}

__global__ void concat_bias(const float* __restrict__ bq, const float* __restrict__ bk,
                            const float* __restrict__ bv, float* __restrict__ bqkv){
    int i = blockIdx.x*blockDim.x + threadIdx.x;
    if (i < 3*HIDN) bqkv[i] = (i < HIDN) ? bq[i] : (i < 2*HIDN ? bk[i-HIDN] : bv[i-2*HIDN]);
}

// one block per row of 512 scores
__global__ __launch_bounds__(256)
void softmax_rows(const float* __restrict__ scores, bf16* __restrict__ probs)
{
    __shared__ float red[8];
    long row = blockIdx.x;
    const float* s = scores + row*SEQ;
    bf16* p = probs + row*SEQ;
    int t = threadIdx.x;
    int wave = t>>6, lane = t&63;
    float a = s[t], b2 = s[t+256];
    float m = fmaxf(a,b2);
    #pragma unroll
    for (int o=32;o>0;o>>=1) m = fmaxf(m, __shfl_xor(m,o,64));
    if (lane==0) red[wave]=m;
    __syncthreads();
    m = fmaxf(fmaxf(red[0],red[1]),fmaxf(red[2],red[3]));
    float e0 = __expf(a-m), e1 = __expf(b2-m);
    float sum = e0+e1;
    #pragma unroll
    for (int o=32;o>0;o>>=1) sum += __shfl_xor(sum,o,64);
    __syncthreads();
    if (lane==0) red[4+wave]=sum;
    __syncthreads();
    sum = red[4]+red[5]+red[6]+red[7];
    float inv = 1.0f/sum;
    p[t]     = f2bf(e0*inv);
    p[t+256] = f2bf(e1*inv);
}

// out = LN(hidden + out_acc + (sum w_a)*bout)
__global__ __launch_bounds__(256)
void add_ln(const float* __restrict__ hidden, const float* __restrict__ out_acc,
            const float* __restrict__ bout, const float* __restrict__ w_a,
            const float* __restrict__ gamma, const float* __restrict__ beta,
            float* __restrict__ out)
{
    __shared__ float red[8];
    int row = blockIdx.x;
    int t = threadIdx.x;
    int wave = t>>6, lane = t&63;
    float swa = 0.f;
    #pragma unroll
    for (int h=0;h<NH;h++) swa += w_a[h];
    float x[3];
    float sum = 0.f;
    #pragma unroll
    for (int j=0;j<3;j++){
        int c = j*256 + t;
        x[j] = hidden[(long)row*HIDN + c] + out_acc[(long)row*HIDN + c] + swa*bout[c];
        sum += x[j];
    }
    #pragma unroll
    for (int o=32;o>0;o>>=1) sum += __shfl_xor(sum,o,64);
    if (lane==0) red[wave]=sum;
    __syncthreads();
    sum = red[0]+red[1]+red[2]+red[3];
    float u = sum * (1.0f/768.0f);
    float vs = 0.f;
    #pragma unroll
    for (int j=0;j<3;j++){ float d = x[j]-u; vs += d*d; }
    #pragma unroll
    for (int o=32;o>0;o>>=1) vs += __shfl_xor(vs,o,64);
    __syncthreads();
    if (lane==0) red[4+wave]=vs;
    __syncthreads();
    vs = red[4]+red[5]+red[6]+red[7];
    float rstd = rsqrtf(vs*(1.0f/768.0f) + 1e-12f);
    #pragma unroll
    for (int j=0;j<3;j++){
        int c = j*256 + t;
        out[(long)row*HIDN + c] = gamma[c]*(x[j]-u)*rstd + beta[c];
    }
}

extern "C" void kernel_launch(void* const* d_in, const int* in_sizes, int n_in,
                              void* d_out, int out_size, void* d_ws, size_t ws_size,
                              hipStream_t stream)
{
    const float* hidden = (const float*)d_in[0];
    const float* mask   = (const float*)d_in[1];
    const float* Wq = (const float*)d_in[2];
    const float* bq = (const float*)d_in[3];
    const float* Wk = (const float*)d_in[4];
    const float* bk = (const float*)d_in[5];
    const float* Wv = (const float*)d_in[6];
    const float* bv = (const float*)d_in[7];
    const float* Wo = (const float*)d_in[8];
    const float* bo = (const float*)d_in[9];
    const float* w_kp = (const float*)d_in[10];
    const float* w_a  = (const float*)d_in[11];
    const float* Wi = (const float*)d_in[12];
    const float* bi = (const float*)d_in[13];
    const float* Wout = (const float*)d_in[14];
    const float* boutp = (const float*)d_in[15];
    const float* gamma = (const float*)d_in[16];
    const float* beta  = (const float*)d_in[17];
    float* out = (float*)d_out;

    char* w = (char*)d_ws;
    auto alloc = [&](size_t bytes)->char* {
        char* p = w; w += (bytes + 255) & ~(size_t)255; return p;
    };
    bf16*  hbf    = (bf16*) alloc((size_t)NTOK*HIDN*2);
    bf16*  WqkvT  = (bf16*) alloc((size_t)3*HIDN*HIDN*2);
    float* bqkv   = (float*)alloc((size_t)3*HIDN*4);
    bf16*  WoT    = (bf16*) alloc((size_t)NH*HIDN*HD*2);
    bf16*  WiT    = (bf16*) alloc((size_t)ISZ*HIDN*2);
    bf16*  WoutT  = (bf16*) alloc((size_t)HIDN*ISZ*2);
    bf16*  qkv    = (bf16*) alloc((size_t)NTOK*3*HIDN*2);
    bf16*  ctx    = (bf16*) alloc((size_t)NH*NTOK*HD*2);
    float* out_acc= (float*)alloc((size_t)NTOK*HIDN*4);
    size_t fixed = (size_t)(w - (char*)d_ws);
    size_t avail = ws_size > fixed ? ws_size - fixed : 0;

    // attention group size ZB (z = (b,h) pairs processed together)
    const size_t perZ = (size_t)SEQ*SEQ*4 + (size_t)SEQ*SEQ*2 + (size_t)128*SEQ*2;
    int ZB = 48;
    while (ZB > 6 && perZ*(size_t)ZB > avail) ZB >>= 1;
    // FFN head chunk HC (no outh buffer anymore: FFN2 atomics into out_acc)
    const size_t perH = (size_t)NTOK*HIDN*2 + (size_t)NTOK*ISZ*2;
    static const int hcs[6] = {12,6,4,3,2,1};
    int HC = 1;
    for (int i=0;i<6;i++){ if (perH*(size_t)hcs[i] <= avail){ HC = hcs[i]; break; } }

    char* big = w;   // shared region: attention views, then FFN chunk views
    float* scores = (float*)big;
    bf16*  probs  = (bf16*)(big + (size_t)ZB*SEQ*SEQ*4);
    bf16*  Vt     = (bf16*)(big + (size_t)ZB*SEQ*SEQ*4 + (size_t)ZB*SEQ*SEQ*2);
    bf16*  xbuf   = (bf16*)big;
    bf16*  inter  = (bf16*)(big + (size_t)HC*NTOK*HIDN*2);

    // ---- prep: convert / transpose weights ----
    cvt_bf16<<<(NTOK*HIDN+255)/256, 256, 0, stream>>>(hidden, hbf, NTOK*HIDN);
    concat_bias<<<(3*HIDN+255)/256, 256, 0, stream>>>(bq, bk, bv, bqkv);
    transpose_cvt<<<dim3(HIDN/32, HIDN/32, 1), 256, 0, stream>>>(Wq, WqkvT,              HIDN, HIDN, 0, 0);
    transpose_cvt<<<dim3(HIDN/32, HIDN/32, 1), 256, 0, stream>>>(Wk, WqkvT + HIDN*HIDN,  HIDN, HIDN, 0, 0);
    transpose_cvt<<<dim3(HIDN/32, HIDN/32, 1), 256, 0, stream>>>(Wv, WqkvT + 2*HIDN*HIDN,HIDN, HIDN, 0, 0);
    transpose_cvt<<<dim3(ISZ/32,  HIDN/32, 1), 256, 0, stream>>>(Wi,   WiT,   HIDN, ISZ, 0, 0);
    transpose_cvt<<<dim3(HIDN/32, ISZ/32,  1), 256, 0, stream>>>(Wout, WoutT, ISZ, HIDN, 0, 0);
    transpose_cvt<<<dim3(HIDN/32, HD/32,  NH), 256, 0, stream>>>(Wo,   WoT,   HD, HIDN,
                                                                 (long)HD*HIDN, (long)HIDN*HD);

    // ---- QKV projection: [2048,768] @ [2304,768]^T ----
    gemm_bt<0><<<dim3(3*HIDN/128, NTOK/128, 1), 256, 0, stream>>>(
        hbf, WqkvT, qkv, bqkv, nullptr,
        HIDN, HIDN, HIDN, 3*HIDN, 3*HIDN,
        0, 1, 0,
        0,0,0, 0,0,0, 0,0,0, 0);

    // ---- attention ----
    hipMemsetAsync(Vt, 0, (size_t)ZB*128*SEQ*2, stream);  // zero-pad Vt rows 64..127
    for (int g = 0; g < 48; g += ZB) {
        transpose_v<<<dim3(2,16,ZB), 256, 0, stream>>>(qkv, Vt, g);
        // scores[bz][q][k] = (Q_bh @ K_bh^T)*0.125 + mask[b][k]
        gemm_bt<4><<<dim3(SEQ/128, SEQ/128, ZB), 256, 0, stream>>>(
            qkv, qkv + HIDN, scores, mask, nullptr,
            HD, 3*HIDN, 3*HIDN, SEQ, SEQ,
            g, NH, 0,
            (long)SEQ*3*HIDN, HD, 0,
            (long)SEQ*3*HIDN, HD, 0,
            0, 0, (long)SEQ*SEQ,
            SEQ);
        softmax_rows<<<ZB*SEQ, 256, 0, stream>>>(scores, probs);
        // ctx[h][b*512+s][d] = probs @ V  (N=64 valid of 128)
        gemm_bt<5><<<dim3(1, SEQ/128, ZB), 256, 0, stream>>>(
            probs, Vt, ctx, nullptr, nullptr,
            SEQ, SEQ, SEQ, HD, HD,
            g, NH, 0,
            0, 0, (long)SEQ*SEQ,
            0, 0, (long)128*SEQ,
            (long)SEQ*HD, (long)NTOK*HD, 0,
            0);
    }

    // ---- per-head Wo -> FFN, in chunks of HC heads; FFN2 accumulates ----
    hipMemsetAsync(out_acc, 0, (size_t)NTOK*HIDN*4, stream);
    for (int c = 0; c < NH; c += HC) {
        // x[h_local] = w_kp[h]*(ctx_h @ Wo_h^T + bo_h)   [2048,64]@[768,64]^T
        gemm_bt<1><<<dim3(HIDN/128, NTOK/128, HC), 256, 0, stream>>>(
            ctx, WoT, xbuf, bo, w_kp,
            HD, HD, HD, HIDN, HIDN,
            c, 1, 0,
            (long)NTOK*HD, 0, 0,
            (long)HIDN*HD, 0, 0,
            0, 0, (long)NTOK*HIDN,
            HIDN);
        // inter = gelu(x @ Wi^T + bi)   [HC*2048,768]@[3072,768]^T
        gemm_bt<2><<<dim3(ISZ/128, HC*NTOK/128, 1), 256, 0, stream>>>(
            xbuf, WiT, inter, bi, nullptr,
            HIDN, HIDN, HIDN, ISZ, ISZ,
            0, 1, 0,
            0,0,0, 0,0,0, 0,0,0, 0);
        // out_acc[token] += w_a[h]*(inter @ Wout^T)   [HC*2048,3072]@[768,3072]^T
        gemm_bt<3><<<dim3(HIDN/128, HC*NTOK/128, 1), 256, 0, stream>>>(
            inter, WoutT, out_acc, nullptr, w_a,
            ISZ, ISZ, ISZ, HIDN, HIDN,
            0, 1, c,
            0,0,0, 0,0,0, 0,0,0, 0);
    }

    // ---- residual + sum(w_a)*bout + LayerNorm ----
    add_ln<<<NTOK, 256, 0, stream>>>(hidden, out_acc, boutp, w_a, gamma, beta, out);
}

// Round 3
// 470.268 us; speedup vs baseline: 1.1750x; 1.0564x over previous
//
#include <hip/hip_runtime.h>
#include <hip/hip_bf16.h>
#include <math.h>

typedef __hip_bfloat16 bf16;
typedef __attribute__((ext_vector_type(4))) float f32x4;
typedef __attribute__((ext_vector_type(8))) short short8;

#define HIDN 768
#define NTOK 2048   // B*S
#define NH 12
#define HD 64
#define ISZ 3072
#define SEQ 512

__device__ __forceinline__ bf16 f2bf(float x){ return __float2bfloat16(x); }
__device__ __forceinline__ float gelu_f(float x){ return 0.5f*x*(1.0f + erff(x*0.70710678118654752f)); }

// async global->LDS, 16B per lane (LDS dest = wave base + lane*16)
__device__ __forceinline__ void gload16(const bf16* g, bf16* l){
    __builtin_amdgcn_global_load_lds(
        (const __attribute__((address_space(1))) unsigned int*)g,
        (__attribute__((address_space(3))) unsigned int*)l,
        16, 0, 0);
}

// ---------------------------------------------------------------------------
// Deep-pipelined GEMM for the big FFN matmuls: C = A[M,K] @ B[N,K]^T.
// BM=128, BN=256, BK=64, 512 threads (8 waves as 2M x 4N, 64x64 per wave).
// 3 LDS buffers x (A 16KB + B 32KB) = 144 KB; prefetch depth 2;
// one raw s_barrier + counted s_waitcnt vmcnt(6) per K-tile (T3/T4);
// full-XOR LDS swizzle granule ^= row&7 via pre-swizzled global source (T2);
// setprio around MFMA clusters (T5); XCD-bijective block swizzle (T1).
// EPI: 2 = gelu(v+bias), bf16 out      (FFN1)
//      3 = atomicAdd(C[(row&2047)*ldc+col], v*scales[sb+(row>>11)]) (FFN2)
// Requires M%128==0, N%256==0, K%64==0, K/64 >= 2.
// ---------------------------------------------------------------------------
template<int EPI>
__global__ __launch_bounds__(512, 2)
void gemm256(const bf16* __restrict__ Abase, const bf16* __restrict__ Bbase,
             void* __restrict__ Cbase, const float* __restrict__ bias,
             const float* __restrict__ scales, int scale_base,
             int K, int lda, int ldb, int ldc)
{
    __shared__ __align__(16) char lds[3*49152];   // 144 KB

    // XCD-aware bijective swizzle
    int nwg  = gridDim.x * gridDim.y;
    int orig = blockIdx.y * gridDim.x + blockIdx.x;
    int q8 = nwg >> 3, r8 = nwg & 7;
    int xcd = orig & 7, idx = orig >> 3;
    int wg = (xcd < r8 ? xcd*(q8+1) : r8*(q8+1) + (xcd-r8)*q8) + idx;
    int bn = wg % gridDim.x, bm = wg / gridDim.x;

    int t = threadIdx.x;
    int lane = t & 63;
    int wave = t >> 6;
    int wm = (wave >> 2) << 6;        // 0 / 64
    int wn = (wave & 3) << 6;         // 0,64,128,192
    int lr = lane & 15, lg = lane >> 4;
    int lr2 = (lr >> 2) & 1;

    // staging: thread t covers (row = t>>3 within 64-row band, source granule
    // pre-swizzled so that linear LDS dest holds granule g_log = g_lin ^ (row&7))
    int srow = t >> 3;                      // 0..63
    int glog = (t & 7) ^ (srow & 7);        // pre-swizzled source granule
    const bf16* Ag0 = Abase + (long)(bm*128 +       srow)*lda + glog*8;
    const bf16* Ag1 = Abase + (long)(bm*128 + 64  + srow)*lda + glog*8;
    const bf16* Bg0 = Bbase + (long)(bn*256 +       srow)*ldb + glog*8;
    const bf16* Bg1 = Bbase + (long)(bn*256 + 64  + srow)*ldb + glog*8;
    const bf16* Bg2 = Bbase + (long)(bn*256 + 128 + srow)*ldb + glog*8;
    const bf16* Bg3 = Bbase + (long)(bn*256 + 192 + srow)*ldb + glog*8;
    int dst = t*16;   // byte slot within each 8KB band

#define STAGE(WOFF) do { \
    char* Lb = lds + (WOFF); \
    gload16(Ag0, (bf16*)(Lb           + dst)); \
    gload16(Ag1, (bf16*)(Lb + 8192    + dst)); \
    gload16(Bg0, (bf16*)(Lb + 16384   + dst)); \
    gload16(Bg1, (bf16*)(Lb + 24576   + dst)); \
    gload16(Bg2, (bf16*)(Lb + 32768   + dst)); \
    gload16(Bg3, (bf16*)(Lb + 40960   + dst)); \
    Ag0 += 64; Ag1 += 64; Bg0 += 64; Bg1 += 64; Bg2 += 64; Bg3 += 64; \
} while(0)

    // ds_read granule byte offsets for kstep 0/1 (granule = ((ks^lr2)<<2)|(lg^(lr&3)))
    int gb0 = ((lr2    ) << 6) | ((lg ^ (lr & 3)) << 4);
    int gb1 = ((lr2 ^ 1) << 6) | ((lg ^ (lr & 3)) << 4);
    int aoff = (wm + lr) * 128;            // A region base (row part)
    int boff = 16384 + (wn + lr) * 128;    // B region base

    f32x4 acc[4][4] = {};
    int rd = 0, wr = 2;

#define BODY(DO_STAGE, VMW) do { \
    int rdo = rd * 49152; \
    if (DO_STAGE) { STAGE(wr * 49152); } \
    short8 a0[4], b0[4], a1[4], b1[4]; \
    _Pragma("unroll") for (int m=0;m<4;m++) a0[m] = *(const short8*)(lds + rdo + aoff + m*2048 + gb0); \
    _Pragma("unroll") for (int n=0;n<4;n++) b0[n] = *(const short8*)(lds + rdo + boff + n*2048 + gb0); \
    __builtin_amdgcn_s_setprio(1); \
    _Pragma("unroll") for (int m=0;m<4;m++) \
        _Pragma("unroll") for (int n=0;n<4;n++) \
            acc[m][n] = __builtin_amdgcn_mfma_f32_16x16x32_bf16(a0[m], b0[n], acc[m][n], 0,0,0); \
    __builtin_amdgcn_s_setprio(0); \
    _Pragma("unroll") for (int m=0;m<4;m++) a1[m] = *(const short8*)(lds + rdo + aoff + m*2048 + gb1); \
    _Pragma("unroll") for (int n=0;n<4;n++) b1[n] = *(const short8*)(lds + rdo + boff + n*2048 + gb1); \
    __builtin_amdgcn_s_setprio(1); \
    _Pragma("unroll") for (int m=0;m<4;m++) \
        _Pragma("unroll") for (int n=0;n<4;n++) \
            acc[m][n] = __builtin_amdgcn_mfma_f32_16x16x32_bf16(a1[m], b1[n], acc[m][n], 0,0,0); \
    __builtin_amdgcn_s_setprio(0); \
    if (VMW == 6)      asm volatile("s_waitcnt vmcnt(6)" ::: "memory"); \
    else               asm volatile("s_waitcnt vmcnt(0)" ::: "memory"); \
    __builtin_amdgcn_s_barrier(); \
    rd++; if (rd == 3) rd = 0; \
    wr++; if (wr == 3) wr = 0; \
} while(0)

    // prologue: stage tiles 0,1 -> buffers 0,1; wait tile0 (retire oldest 6)
    STAGE(0);
    STAGE(49152);
    asm volatile("s_waitcnt vmcnt(6)" ::: "memory");
    __builtin_amdgcn_s_barrier();

    int NT = K >> 6;
    for (int kt = 0; kt < NT - 2; ++kt) BODY(1, 6);
    BODY(0, 0);
    BODY(0, 0);

#undef BODY
#undef STAGE

    // epilogue: C/D layout col=lane&15, row=(lane>>4)*4 + i
    #pragma unroll
    for (int m=0;m<4;m++){
        #pragma unroll
        for (int n=0;n<4;n++){
            int col = bn*256 + wn + n*16 + lr;
            float bcol = (EPI==2) ? bias[col] : 0.f;
            #pragma unroll
            for (int i=0;i<4;i++){
                long row = (long)bm*128 + wm + m*16 + lg*4 + i;
                float v = acc[m][n][i];
                if constexpr (EPI==2){
                    ((bf16*)Cbase)[row*ldc+col] = f2bf(gelu_f(v + bcol));
                } else {
                    unsafeAtomicAdd((float*)Cbase + (row & (NTOK-1))*ldc + col,
                                    v * scales[scale_base + (int)(row>>11)]);
                }
            }
        }
    }
}

// ---------------------------------------------------------------------------
// Generic bf16 GEMM (m97 structure) for the smaller/odd-shaped matmuls.
// EPI: 0 = bias, bf16 out              (QKV)
//      1 = scale[zq]*(v+bias), bf16    (per-head Wo, scale=w_kp)
//      4 = v*0.125 + bias[col], f32    (attention scores + mask)
//      5 = bf16 out, col<Nvalid guard  (PV)
// ---------------------------------------------------------------------------
template<int EPI>
__global__ __launch_bounds__(256)
void gemm_bt(const bf16* __restrict__ Abase, const bf16* __restrict__ Bbase,
             void* __restrict__ Cbase, const float* __restrict__ biasBase,
             const float* __restrict__ scales,
             int K, int lda, int ldb, int ldc, int Nvalid,
             int zb0, int zdiv, int scale_base,
             long sAq, long sAr, long sAz,
             long sBq, long sBr, long sBz,
             long sCq, long sCr, long sCz,
             long sBiasq)
{
    int bz = blockIdx.z;
    int za = zb0 + bz;
    int zq = za / zdiv, zr = za - zq*zdiv;
    const bf16* A = Abase + (long)zq*sAq + (long)zr*sAr + (long)bz*sAz;
    const bf16* B = Bbase + (long)zq*sBq + (long)zr*sBr + (long)bz*sBz;
    const float* bias = biasBase ? (biasBase + (long)zq*sBiasq) : nullptr;
    long coff = (long)zq*sCq + (long)zr*sCr + (long)bz*sCz;

    __shared__ bf16 As[128*32];
    __shared__ bf16 Bs[128*32];

    int nwg  = gridDim.x * gridDim.y;
    int orig = blockIdx.y * gridDim.x + blockIdx.x;
    int q8 = nwg >> 3, r8 = nwg & 7;
    int xcd = orig & 7, idx = orig >> 3;
    int wg = (xcd < r8 ? xcd*(q8+1) : r8*(q8+1) + (xcd-r8)*q8) + idx;
    int bn = wg % gridDim.x, bm = wg / gridDim.x;

    int t = threadIdx.x;
    int wave = t >> 6, lane = t & 63;
    int wm = (wave >> 1) << 6;   // 0 or 64
    int wn = (wave & 1) << 6;
    int lr = lane & 15, lg = lane >> 4;

    f32x4 acc[4][4] = {};

    int arow = t >> 2;              // 0..63
    int acol = (t & 3) << 3;        // 0,8,16,24
    const bf16* Ag0 = A + (long)(bm*128 + arow)*lda + acol;
    const bf16* Ag1 = Ag0 + (long)64*lda;
    const bf16* Bg0 = B + (long)(bn*128 + arow)*ldb + acol;
    const bf16* Bg1 = Bg0 + (long)64*ldb;
    bf16* Al = As + t*8;
    bf16* Bl = Bs + t*8;

    for (int k0 = 0; k0 < K; k0 += 32) {
        __syncthreads();
        gload16(Ag0, Al);
        gload16(Ag1, Al + 64*32);
        gload16(Bg0, Bl);
        gload16(Bg1, Bl + 64*32);
        Ag0 += 32; Ag1 += 32; Bg0 += 32; Bg1 += 32;
        __syncthreads();
        short8 af[4], bfr[4];
        #pragma unroll
        for (int m=0;m<4;m++) af[m]  = *(short8*)&As[(wm + m*16 + lr)*32 + lg*8];
        #pragma unroll
        for (int n=0;n<4;n++) bfr[n] = *(short8*)&Bs[(wn + n*16 + lr)*32 + lg*8];
        #pragma unroll
        for (int m=0;m<4;m++)
            #pragma unroll
            for (int n=0;n<4;n++)
                acc[m][n] = __builtin_amdgcn_mfma_f32_16x16x32_bf16(af[m], bfr[n], acc[m][n], 0,0,0);
    }

    #pragma unroll
    for (int m=0;m<4;m++){
        #pragma unroll
        for (int n=0;n<4;n++){
            int col = bn*128 + wn + n*16 + lr;
            float bcol = 0.f;
            if constexpr (EPI==0||EPI==1||EPI==4) bcol = bias[col];
            #pragma unroll
            for (int i=0;i<4;i++){
                long row = (long)bm*128 + wm + m*16 + lg*4 + i;
                float v = acc[m][n][i];
                if constexpr (EPI==0){
                    ((bf16*)Cbase + coff)[row*ldc+col] = f2bf(v + bcol);
                } else if constexpr (EPI==1){
                    ((bf16*)Cbase + coff)[row*ldc+col] = f2bf(scales[zq]*(v + bcol));
                } else if constexpr (EPI==4){
                    ((float*)Cbase + coff)[row*ldc+col] = v*0.125f + bcol;
                } else {
                    if (col < Nvalid) ((bf16*)Cbase + coff)[row*ldc+col] = f2bf(v);
                }
            }
        }
    }
}

// ---------------------------------------------------------------------------
__global__ __launch_bounds__(256)
void transpose_cvt(const float* __restrict__ src, bf16* __restrict__ dst,
                   int R, int C, long sSrcZ, long sDstZ)
{
    __shared__ float tile[32][33];
    src += (long)blockIdx.z * sSrcZ;
    dst += (long)blockIdx.z * sDstZ;
    int c0 = blockIdx.x*32, r0 = blockIdx.y*32;
    int tx = threadIdx.x & 31, ty = threadIdx.x >> 5;
    #pragma unroll
    for (int i=0;i<32;i+=8) tile[ty+i][tx] = src[(long)(r0+ty+i)*C + c0+tx];
    __syncthreads();
    #pragma unroll
    for (int i=0;i<32;i+=8) dst[(long)(c0+ty+i)*R + r0+tx] = f2bf(tile[tx][ty+i]);
}

__global__ __launch_bounds__(256)
void transpose_v(const bf16* __restrict__ qkv, bf16* __restrict__ Vt, int zb0)
{
    __shared__ bf16 tile[32][33];
    int za = zb0 + blockIdx.z; int b = za/NH, h = za - b*NH;
    const bf16* src = qkv + (long)b*SEQ*3*HIDN + 2*HIDN + h*HD;
    bf16* dst = Vt + (long)blockIdx.z*128*SEQ;
    int d0 = blockIdx.x*32, s0 = blockIdx.y*32;
    int tx = threadIdx.x & 31, ty = threadIdx.x >> 5;
    #pragma unroll
    for (int i=0;i<32;i+=8) tile[ty+i][tx] = src[(long)(s0+ty+i)*(3*HIDN) + d0+tx];
    __syncthreads();
    #pragma unroll
    for (int i=0;i<32;i+=8) dst[(long)(d0+ty+i)*SEQ + s0+tx] = tile[tx][ty+i];
}

__global__ void cvt_bf16(const float* __restrict__ in, bf16* __restrict__ out, int n){
    int i = blockIdx.x*blockDim.x + threadIdx.x;
    if (i < n) out[i] = f2bf(in[i]);
}

__global__ void concat_bias(const float* __restrict__ bq, const float* __restrict__ bk,
                            const float* __restrict__ bv, float* __restrict__ bqkv){
    int i = blockIdx.x*blockDim.x + threadIdx.x;
    if (i < 3*HIDN) bqkv[i] = (i < HIDN) ? bq[i] : (i < 2*HIDN ? bk[i-HIDN] : bv[i-2*HIDN]);
}

__global__ __launch_bounds__(256)
void softmax_rows(const float* __restrict__ scores, bf16* __restrict__ probs)
{
    __shared__ float red[8];
    long row = blockIdx.x;
    const float* s = scores + row*SEQ;
    bf16* p = probs + row*SEQ;
    int t = threadIdx.x;
    int wave = t>>6, lane = t&63;
    float a = s[t], b2 = s[t+256];
    float m = fmaxf(a,b2);
    #pragma unroll
    for (int o=32;o>0;o>>=1) m = fmaxf(m, __shfl_xor(m,o,64));
    if (lane==0) red[wave]=m;
    __syncthreads();
    m = fmaxf(fmaxf(red[0],red[1]),fmaxf(red[2],red[3]));
    float e0 = __expf(a-m), e1 = __expf(b2-m);
    float sum = e0+e1;
    #pragma unroll
    for (int o=32;o>0;o>>=1) sum += __shfl_xor(sum,o,64);
    __syncthreads();
    if (lane==0) red[4+wave]=sum;
    __syncthreads();
    sum = red[4]+red[5]+red[6]+red[7];
    float inv = 1.0f/sum;
    p[t]     = f2bf(e0*inv);
    p[t+256] = f2bf(e1*inv);
}

__global__ __launch_bounds__(256)
void add_ln(const float* __restrict__ hidden, const float* __restrict__ out_acc,
            const float* __restrict__ bout, const float* __restrict__ w_a,
            const float* __restrict__ gamma, const float* __restrict__ beta,
            float* __restrict__ out)
{
    __shared__ float red[8];
    int row = blockIdx.x;
    int t = threadIdx.x;
    int wave = t>>6, lane = t&63;
    float swa = 0.f;
    #pragma unroll
    for (int h=0;h<NH;h++) swa += w_a[h];
    float x[3];
    float sum = 0.f;
    #pragma unroll
    for (int j=0;j<3;j++){
        int c = j*256 + t;
        x[j] = hidden[(long)row*HIDN + c] + out_acc[(long)row*HIDN + c] + swa*bout[c];
        sum += x[j];
    }
    #pragma unroll
    for (int o=32;o>0;o>>=1) sum += __shfl_xor(sum,o,64);
    if (lane==0) red[wave]=sum;
    __syncthreads();
    sum = red[0]+red[1]+red[2]+red[3];
    float u = sum * (1.0f/768.0f);
    float vs = 0.f;
    #pragma unroll
    for (int j=0;j<3;j++){ float d = x[j]-u; vs += d*d; }
    #pragma unroll
    for (int o=32;o>0;o>>=1) vs += __shfl_xor(vs,o,64);
    __syncthreads();
    if (lane==0) red[4+wave]=vs;
    __syncthreads();
    vs = red[4]+red[5]+red[6]+red[7];
    float rstd = rsqrtf(vs*(1.0f/768.0f) + 1e-12f);
    #pragma unroll
    for (int j=0;j<3;j++){
        int c = j*256 + t;
        out[(long)row*HIDN + c] = gamma[c]*(x[j]-u)*rstd + beta[c];
    }
}

extern "C" void kernel_launch(void* const* d_in, const int* in_sizes, int n_in,
                              void* d_out, int out_size, void* d_ws, size_t ws_size,
                              hipStream_t stream)
{
    const float* hidden = (const float*)d_in[0];
    const float* mask   = (const float*)d_in[1];
    const float* Wq = (const float*)d_in[2];
    const float* bq = (const float*)d_in[3];
    const float* Wk = (const float*)d_in[4];
    const float* bk = (const float*)d_in[5];
    const float* Wv = (const float*)d_in[6];
    const float* bv = (const float*)d_in[7];
    const float* Wo = (const float*)d_in[8];
    const float* bo = (const float*)d_in[9];
    const float* w_kp = (const float*)d_in[10];
    const float* w_a  = (const float*)d_in[11];
    const float* Wi = (const float*)d_in[12];
    const float* bi = (const float*)d_in[13];
    const float* Wout = (const float*)d_in[14];
    const float* boutp = (const float*)d_in[15];
    const float* gamma = (const float*)d_in[16];
    const float* beta  = (const float*)d_in[17];
    float* out = (float*)d_out;

    char* w = (char*)d_ws;
    auto alloc = [&](size_t bytes)->char* {
        char* p = w; w += (bytes + 255) & ~(size_t)255; return p;
    };
    bf16*  hbf    = (bf16*) alloc((size_t)NTOK*HIDN*2);
    bf16*  WqkvT  = (bf16*) alloc((size_t)3*HIDN*HIDN*2);
    float* bqkv   = (float*)alloc((size_t)3*HIDN*4);
    bf16*  WoT    = (bf16*) alloc((size_t)NH*HIDN*HD*2);
    bf16*  WiT    = (bf16*) alloc((size_t)ISZ*HIDN*2);
    bf16*  WoutT  = (bf16*) alloc((size_t)HIDN*ISZ*2);
    bf16*  qkv    = (bf16*) alloc((size_t)NTOK*3*HIDN*2);
    bf16*  ctx    = (bf16*) alloc((size_t)NH*NTOK*HD*2);
    float* out_acc= (float*)alloc((size_t)NTOK*HIDN*4);
    size_t fixed = (size_t)(w - (char*)d_ws);
    size_t avail = ws_size > fixed ? ws_size - fixed : 0;

    const size_t perZ = (size_t)SEQ*SEQ*4 + (size_t)SEQ*SEQ*2 + (size_t)128*SEQ*2;
    int ZB = 48;
    while (ZB > 6 && perZ*(size_t)ZB > avail) ZB >>= 1;
    const size_t perH = (size_t)NTOK*HIDN*2 + (size_t)NTOK*ISZ*2;
    static const int hcs[6] = {12,6,4,3,2,1};
    int HC = 1;
    for (int i=0;i<6;i++){ if (perH*(size_t)hcs[i] <= avail){ HC = hcs[i]; break; } }

    char* big = w;
    float* scores = (float*)big;
    bf16*  probs  = (bf16*)(big + (size_t)ZB*SEQ*SEQ*4);
    bf16*  Vt     = (bf16*)(big + (size_t)ZB*SEQ*SEQ*4 + (size_t)ZB*SEQ*SEQ*2);
    bf16*  xbuf   = (bf16*)big;
    bf16*  inter  = (bf16*)(big + (size_t)HC*NTOK*HIDN*2);

    // ---- prep ----
    cvt_bf16<<<(NTOK*HIDN+255)/256, 256, 0, stream>>>(hidden, hbf, NTOK*HIDN);
    concat_bias<<<(3*HIDN+255)/256, 256, 0, stream>>>(bq, bk, bv, bqkv);
    transpose_cvt<<<dim3(HIDN/32, HIDN/32, 1), 256, 0, stream>>>(Wq, WqkvT,              HIDN, HIDN, 0, 0);
    transpose_cvt<<<dim3(HIDN/32, HIDN/32, 1), 256, 0, stream>>>(Wk, WqkvT + HIDN*HIDN,  HIDN, HIDN, 0, 0);
    transpose_cvt<<<dim3(HIDN/32, HIDN/32, 1), 256, 0, stream>>>(Wv, WqkvT + 2*HIDN*HIDN,HIDN, HIDN, 0, 0);
    transpose_cvt<<<dim3(ISZ/32,  HIDN/32, 1), 256, 0, stream>>>(Wi,   WiT,   HIDN, ISZ, 0, 0);
    transpose_cvt<<<dim3(HIDN/32, ISZ/32,  1), 256, 0, stream>>>(Wout, WoutT, ISZ, HIDN, 0, 0);
    transpose_cvt<<<dim3(HIDN/32, HD/32,  NH), 256, 0, stream>>>(Wo,   WoT,   HD, HIDN,
                                                                 (long)HD*HIDN, (long)HIDN*HD);

    // ---- QKV projection ----
    gemm_bt<0><<<dim3(3*HIDN/128, NTOK/128, 1), 256, 0, stream>>>(
        hbf, WqkvT, qkv, bqkv, nullptr,
        HIDN, HIDN, HIDN, 3*HIDN, 3*HIDN,
        0, 1, 0,
        0,0,0, 0,0,0, 0,0,0, 0);

    // ---- attention ----
    hipMemsetAsync(Vt, 0, (size_t)ZB*128*SEQ*2, stream);
    for (int g = 0; g < 48; g += ZB) {
        transpose_v<<<dim3(2,16,ZB), 256, 0, stream>>>(qkv, Vt, g);
        gemm_bt<4><<<dim3(SEQ/128, SEQ/128, ZB), 256, 0, stream>>>(
            qkv, qkv + HIDN, scores, mask, nullptr,
            HD, 3*HIDN, 3*HIDN, SEQ, SEQ,
            g, NH, 0,
            (long)SEQ*3*HIDN, HD, 0,
            (long)SEQ*3*HIDN, HD, 0,
            0, 0, (long)SEQ*SEQ,
            SEQ);
        softmax_rows<<<ZB*SEQ, 256, 0, stream>>>(scores, probs);
        gemm_bt<5><<<dim3(1, SEQ/128, ZB), 256, 0, stream>>>(
            probs, Vt, ctx, nullptr, nullptr,
            SEQ, SEQ, SEQ, HD, HD,
            g, NH, 0,
            0, 0, (long)SEQ*SEQ,
            0, 0, (long)128*SEQ,
            (long)SEQ*HD, (long)NTOK*HD, 0,
            0);
    }

    // ---- per-head Wo -> FFN (big GEMMs on gemm256) ----
    hipMemsetAsync(out_acc, 0, (size_t)NTOK*HIDN*4, stream);
    for (int c = 0; c < NH; c += HC) {
        gemm_bt<1><<<dim3(HIDN/128, NTOK/128, HC), 256, 0, stream>>>(
            ctx, WoT, xbuf, bo, w_kp,
            HD, HD, HD, HIDN, HIDN,
            c, 1, 0,
            (long)NTOK*HD, 0, 0,
            (long)HIDN*HD, 0, 0,
            0, 0, (long)NTOK*HIDN,
            HIDN);
        // inter = gelu(x @ Wi^T + bi)   [HC*2048,768]@[3072,768]^T
        gemm256<2><<<dim3(ISZ/256, HC*NTOK/128, 1), 512, 0, stream>>>(
            xbuf, WiT, inter, bi, nullptr, 0,
            HIDN, HIDN, HIDN, ISZ);
        // out_acc[token] += w_a[h]*(inter @ Wout^T)
        gemm256<3><<<dim3(HIDN/256, HC*NTOK/128, 1), 512, 0, stream>>>(
            inter, WoutT, out_acc, nullptr, w_a, c,
            ISZ, ISZ, ISZ, HIDN);
    }

    // ---- residual + sum(w_a)*bout + LayerNorm ----
    add_ln<<<NTOK, 256, 0, stream>>>(hidden, out_acc, boutp, w_a, gamma, beta, out);
}